// Round 16
// baseline (146.512 us; speedup 1.0000x reference)
//
#include <hip/hip_runtime.h>
#include <hip/hip_bf16.h>
#include <math.h>

#define BDIM 4
#define SLEN 4096
#define DDIM 1024
#define MROWS (BDIM*SLEN)      // 16384
#define KDIM DDIM              // 1024
#define NCHUNK 64
#define CLEN (SLEN/NCHUNK)     // 64
#define NCH (BDIM*DDIM)        // 4096
#define NKT (KDIM/32)          // 32 K-steps
#define ABUF 8192              // one A buffer: 4 row-tiles x 2KB (128 rows x 32 k)
#define ALLROWS (MROWS + 2*DDIM)   // 18432 rows in fused cast

typedef __bf16 bf16;
typedef __bf16 bf16x8 __attribute__((ext_vector_type(8)));
typedef float f32x16 __attribute__((ext_vector_type(16)));

__device__ __forceinline__ void gload_lds16(const void* g, void* l) {
  __builtin_amdgcn_global_load_lds(
      (const __attribute__((address_space(1))) unsigned int*)g,
      (__attribute__((address_space(3))) unsigned int*)l, 16, 0, 0);
}

// ---------------- fused cast f32 -> bf16, fragment-order tile swizzle -------
// [R8-verified layout] Tile = 32 rows x 32 k (2KB) at [T][KT]; granule (r,j)
// at slot j*32 + r. Sources x / Wa / Wx concatenated by row (out buffers are
// ws-adjacent: xb | wab | wxb). Reads coalesced; writes permute in 2KB.
__global__ void cast_all_kernel(const float* __restrict__ x, const float* __restrict__ Wa,
                                const float* __restrict__ Wx, bf16* __restrict__ out) {
  const int gid  = blockIdx.x * 256 + threadIdx.x;
  const int tile = gid >> 7, local = gid & 127;
  const int j = local & 3, r = local >> 2;     // coalesced read assignment
  const int T = tile >> 5, KT = tile & 31;
  const int m = T*32 + r;
  const float* src;
  int row;
  if (m < MROWS)              { src = x;  row = m; }
  else if (m < MROWS + DDIM)  { src = Wa; row = m - MROWS; }
  else                        { src = Wx; row = m - MROWS - DDIM; }
  const float4* p = (const float4*)(src + (size_t)row * KDIM + KT*32 + j*8);
  float4 v0 = p[0], v1 = p[1];
  bf16x8 o;
  o[0] = (bf16)v0.x; o[1] = (bf16)v0.y; o[2] = (bf16)v0.z; o[3] = (bf16)v0.w;
  o[4] = (bf16)v1.x; o[5] = (bf16)v1.y; o[6] = (bf16)v1.z; o[7] = (bf16)v1.w;
  ((bf16x8*)out)[(size_t)tile * 128 + j*32 + r] = o;   // fragment-order slot
}

// ---------------- klam2[h] = -C * softplus(-Lam[h]) / ln2 ----------------
__global__ void klam_kernel(const float* __restrict__ Lam, float* __restrict__ klam) {
  int h = blockIdx.x * blockDim.x + threadIdx.x;
  if (h < DDIM) klam[h] = -8.0f * 1.4426950408889634f * log1pf(__expf(-Lam[h]));
}

// ---------------- dual-weight GEMM, A-only LDS + B direct from L2 ----------
// Block 128(M) x 64(N)-dual, 4 waves (2M x 2N), per-wave 64m x 32n-dual,
// 32x32x16 MFMA. A staged via LDS (3 x 8KB buffers, counted vmcnt); B frags
// loaded global->VGPR (contiguous 1KB/wave from frag-order W, L2-resident,
// 2-K-step register lead, static sets per rule #20). LDS bytes per
// block-K-step: 88KB -> 32KB. Phase ordering from R12 (verified).
__global__ __launch_bounds__(256, 3) void gemm_gates_kernel(
    const bf16* __restrict__ xb, const bf16* __restrict__ wab, const bf16* __restrict__ wxb,
    const float* __restrict__ ba, const float* __restrict__ bx,
    const float* __restrict__ klam, bf16* __restrict__ La, bf16* __restrict__ Bp,
    float* __restrict__ sAo, float* __restrict__ sBo)
{
  __shared__ char smem[3*ABUF];   // 24 KB

  const int tid  = threadIdx.x;
  const int wave = tid >> 6, lane = tid & 63;
  const int wm = wave >> 1, wn = wave & 1;       // 2M x 2N waves

  // XCD-bijective swizzle: 2048 blocks, 8 XCDs, 256 each.
  const int orig  = blockIdx.x;
  const int newid = (orig & 7) * 256 + (orig >> 3);
  const int m0 = (newid >> 4) * 128;
  const int h0 = (newid & 15) * 64;

  f32x16 accA0 = (f32x16)0.0f, accA1 = (f32x16)0.0f;
  f32x16 accX0 = (f32x16)0.0f, accX1 = (f32x16)0.0f;

  const int Tb = m0 >> 5;           // first of 4 X row-tiles
  const int Ht = h0 >> 5;           // first of 2 W row-tiles (per weight)
  // A staging: thread stages granule (tid&127) of row-tiles (tid>>7) and +2
  const bf16* aS0 = xb + (size_t)(Tb + (tid >> 7))     * 32768 + (tid & 127) * 8;
  const bf16* aS1 = xb + (size_t)(Tb + 2 + (tid >> 7)) * 32768 + (tid & 127) * 8;

  auto STAGE_A = [&](int KT, char* nb) {
    gload_lds16(aS0 + KT*1024, nb + tid*16);
    gload_lds16(aS1 + KT*1024, nb + 4096 + tid*16);
  };

  // B direct: per-wave contiguous 1KB fragments from frag-order W
  const bf16* baBase = wab + (size_t)(Ht + wn) * 32768 + (size_t)lane * 8;
  const bf16* bxBase = wxb + (size_t)(Ht + wn) * 32768 + (size_t)lane * 8;

#define LOADB(KT, BA0, BA1, BX0, BX1) do {                        \
    const bf16* _pa = baBase + (size_t)(KT) * 1024;               \
    const bf16* _px = bxBase + (size_t)(KT) * 1024;               \
    BA0 = *(const bf16x8*)(_pa);  BA1 = *(const bf16x8*)(_pa + 512); \
    BX0 = *(const bf16x8*)(_px);  BX1 = *(const bf16x8*)(_px + 512); \
  } while (0)

  // per-wave A ds_read offsets (all base + lane*16 -> conflict-free)
  const int aOff = wm*4096 + lane*16;     // subtiles 2wm, 2wm+1

  char* b0 = smem;
  char* b1 = smem + ABUF;
  char* b2 = smem + 2*ABUF;

  bf16x8 ba0_0, ba1_0, bx0_0, bx1_0;      // B set 0 (even kt)
  bf16x8 ba0_1, ba1_1, bx0_1, bx1_1;      // B set 1 (odd kt)

  STAGE_A(0, b0);
  STAGE_A(1, b1);
  LOADB(0, ba0_0, ba1_0, bx0_0, bx1_0);
  LOADB(1, ba0_1, ba1_1, bx0_1, bx1_1);
  asm volatile("s_waitcnt vmcnt(10)" ::: "memory");   // A(0) landed
  __builtin_amdgcn_s_barrier();

  char *pc = b0, *pn = b1, *ps = b2;

#define BODY(KT, BA0, BA1, BX0, BX1) do {                                      \
    bf16x8 a00 = *(const bf16x8*)(pc + aOff);                                  \
    bf16x8 a01 = *(const bf16x8*)(pc + aOff + 1024);                           \
    bf16x8 a10 = *(const bf16x8*)(pc + aOff + 2048);                           \
    bf16x8 a11 = *(const bf16x8*)(pc + aOff + 3072);                           \
    __builtin_amdgcn_sched_barrier(0);                                         \
    if ((KT) + 2 < NKT) STAGE_A((KT) + 2, ps);                                 \
    __builtin_amdgcn_s_barrier();                      /* absorbs ds latency */\
    asm volatile("s_waitcnt lgkmcnt(0)" ::: "memory");                         \
    __builtin_amdgcn_sched_barrier(0);                 /* rule #18 */          \
    __builtin_amdgcn_s_setprio(1);                                             \
    accA0 = __builtin_amdgcn_mfma_f32_32x32x16_bf16(a00, BA0, accA0, 0, 0, 0); \
    accA1 = __builtin_amdgcn_mfma_f32_32x32x16_bf16(a10, BA0, accA1, 0, 0, 0); \
    accX0 = __builtin_amdgcn_mfma_f32_32x32x16_bf16(a00, BX0, accX0, 0, 0, 0); \
    accX1 = __builtin_amdgcn_mfma_f32_32x32x16_bf16(a10, BX0, accX1, 0, 0, 0); \
    accA0 = __builtin_amdgcn_mfma_f32_32x32x16_bf16(a01, BA1, accA0, 0, 0, 0); \
    accA1 = __builtin_amdgcn_mfma_f32_32x32x16_bf16(a11, BA1, accA1, 0, 0, 0); \
    accX0 = __builtin_amdgcn_mfma_f32_32x32x16_bf16(a01, BX1, accX0, 0, 0, 0); \
    accX1 = __builtin_amdgcn_mfma_f32_32x32x16_bf16(a11, BX1, accX1, 0, 0, 0); \
    __builtin_amdgcn_s_setprio(0);                                             \
    if ((KT) + 2 < NKT) LOADB((KT) + 2, BA0, BA1, BX0, BX1);                   \
    if ((KT) + 2 < NKT)      { asm volatile("s_waitcnt vmcnt(10)" ::: "memory"); } \
    else if ((KT) + 1 < NKT) { asm volatile("s_waitcnt vmcnt(4)"  ::: "memory"); } \
    if ((KT) + 1 < NKT) __builtin_amdgcn_s_barrier();                          \
    char* _t = pc; pc = pn; pn = ps; ps = _t;                                  \
  } while (0)

  for (int kt = 0; kt < NKT; kt += 2) {
    BODY(kt,     ba0_0, ba1_0, bx0_0, bx1_0);
    BODY(kt + 1, ba0_1, ba1_1, bx0_1, bx1_1);
  }
#undef BODY
#undef LOADB

  // ---- epilogue ----
  // C/D layout (32x32): col = lane&31, row = (q&3) + 8*(q>>2) + 4*(lane>>5)
  const int colh = h0 + wn*32 + (lane & 31);
  const int hi   = lane >> 5;
  const float bah = ba[colh], bxh = bx[colh], kl = klam[colh];  // kl pre-scaled by 1/ln2
  // x reload from fragment-order xb [R8-verified]
  const size_t xh = (size_t)(colh >> 5) * 1024 + ((colh >> 3) & 3) * 256 + (colh & 7);

  // segment maps: P/S over 4 consecutive rows (g-group), per mt and this hi.
  float P[2][4], S[2][4];
  #pragma unroll
  for (int mt = 0; mt < 2; ++mt) {
    const int mbase = m0 + wm*64 + mt*32;
    const size_t xtb = (size_t)(mbase >> 5) * 32768 + xh;
    const f32x16 aA = mt ? accA1 : accA0;
    const f32x16 aX = mt ? accX1 : accX0;
    #pragma unroll
    for (int g = 0; g < 4; ++g) {
      float Pg = 1.0f, Sg = 0.0f;
      #pragma unroll
      for (int jj = 0; jj < 4; ++jj) {
        const int q   = g*4 + jj;
        const int row = jj + 8*g + 4*hi;          // rows increase with jj
        const int m   = mbase + row;
        const float ga = aA[q] + bah;
        const float gx = aX[q] + bxh;
        const float rt = 1.0f / (1.0f + __expf(-ga));
        const float it = 1.0f / (1.0f + __expf(-gx));
        const float la = kl * rt;                 // log2(a)
        const float a  = exp2f(la);
        const float xv = (float)xb[xtb + (size_t)row * 8];
        const float bb = sqrtf(fmaxf(1.0f - a*a, 0.0f)) * (it * xv);
        La[(size_t)m * DDIM + colh] = (bf16)la;   // log2(a) -> ws (bf16)
        Bp[(size_t)m * DDIM + colh] = (bf16)bb;   // b -> ws (bf16)
        Sg = fmaf(a, Sg, bb);                     // exact a in the summary
        Pg *= a;
      }
      P[mt][g] = Pg; S[mt][g] = Sg;
    }
  }

  // compose the 16 segments in row order: sigma = mt*8 + g*2 + hi'
  float Pc = 1.0f, Sc = 0.0f;
  #pragma unroll
  for (int mt = 0; mt < 2; ++mt) {
    #pragma unroll
    for (int g = 0; g < 4; ++g) {
      const float pm = P[mt][g], sm = S[mt][g];
      const float pp = __shfl_xor(pm, 32);
      const float sp = __shfl_xor(sm, 32);
      const float p0 = hi ? pp : pm, s0 = hi ? sp : sm;   // hi'=0 first
      const float p1 = hi ? pm : pp, s1 = hi ? sm : sp;   // then hi'=1
      Sc = fmaf(p0, Sc, s0); Pc *= p0;
      Sc = fmaf(p1, Sc, s1); Pc *= p1;
    }
  }
  if (hi == 0) {
    const int mb0  = m0 + wm*64;          // chunk start (64-aligned)
    const int bidx = mb0 >> 12;           // batch
    const int c    = (mb0 & (SLEN-1)) >> 6;  // chunk within sequence
    sAo[(size_t)c * NCH + bidx*1024 + colh] = Pc;
    sBo[(size_t)c * NCH + bidx*1024 + colh] = Sc;
  }
}

// ---------------- phase 2: sequential prefix over chunks ----------------
__global__ void scan2_kernel(const float* __restrict__ sA, const float* __restrict__ sB,
                             float* __restrict__ Hin) {
  const int ch = blockIdx.x * 256 + threadIdx.x;
  float h = 0.0f;
  for (int c = 0; c < NCHUNK; ++c) {
    Hin[c * NCH + ch] = h;
    h = fmaf(sA[c * NCH + ch], h, sB[c * NCH + ch]);
  }
}

// ---------------- phase 3: apply (pure streaming; a = 2^la) ----------------
__global__ void scan3_kernel(const bf16* __restrict__ La, const bf16* __restrict__ Bp,
                             const float* __restrict__ Hin, float* __restrict__ y) {
  const int ch = blockIdx.x * 256 + threadIdx.x;
  const int c  = blockIdx.y;
  const int b  = ch >> 10, d = ch & 1023;
  size_t idx = ((size_t)b * SLEN + (size_t)c * CLEN) * DDIM + d;
  float h = Hin[c * NCH + ch];
  #pragma unroll 4
  for (int s = 0; s < CLEN; ++s) {
    const float a = exp2f((float)La[idx]);
    h = fmaf(a, h, (float)Bp[idx]);
    y[idx] = h;
    idx += DDIM;
  }
}

extern "C" void kernel_launch(void* const* d_in, const int* in_sizes, int n_in,
                              void* d_out, int out_size, void* d_ws, size_t ws_size,
                              hipStream_t stream) {
  const float* x   = (const float*)d_in[0];
  const float* Wa  = (const float*)d_in[1];
  const float* Wx  = (const float*)d_in[2];
  const float* ba  = (const float*)d_in[3];
  const float* bx  = (const float*)d_in[4];
  const float* Lam = (const float*)d_in[5];
  float* y = (float*)d_out;

  // workspace layout (bytes): total 108,007,424 (proven budget)
  if (ws_size < 108007424ULL) return;  // insufficient scratch; fail cleanly
  char* ws = (char*)d_ws;
  bf16*  xb   = (bf16*)(ws);                     // 32 MB: x bf16, frag-order
  bf16*  wab  = (bf16*)(ws + 33554432);          //  2 MB, frag-order (adjacent!)
  bf16*  wxb  = (bf16*)(ws + 35651584);          //  2 MB, frag-order (adjacent!)
  bf16*  Bp   = (bf16*)(ws + 37748736);          // 32 MB: b (bf16)
  bf16*  La   = (bf16*)(ws + 71303168);          // 32 MB: log2(a) (bf16)
  float* klam = (float*)(ws + 104857600);        //  4 KB (pre-scaled by 1/ln2)
  float* sA   = (float*)(ws + 104861696);        //  1 MB
  float* sB   = (float*)(ws + 105910272);        //  1 MB
  float* Hin  = (float*)(ws + 106958848);        //  1 MB

  // fused cast: 18432 rows x 1024 k -> 576 row-tiles x 32 k-tiles x 128 granules
  cast_all_kernel<<<(ALLROWS/32)*(KDIM/32)*128/256, 256, 0, stream>>>(x, Wa, Wx, xb);
  klam_kernel<<<DDIM/256, 256, 0, stream>>>(Lam, klam);

  // 2048 blocks: (M/128) * (N/64) = 128 * 16
  gemm_gates_kernel<<<2048, 256, 0, stream>>>(xb, wab, wxb, ba, bx, klam,
                                              La, Bp, sA, sB);

  scan2_kernel<<<NCH/256, 256, 0, stream>>>(sA, sB, Hin);
  dim3 sgrid(NCH/256, NCHUNK);
  scan3_kernel<<<sgrid, 256, 0, stream>>>(La, Bp, Hin, y);
}

// Round 17
// 137.616 us; speedup vs baseline: 1.0646x; 1.0646x over previous
//
#include <hip/hip_runtime.h>
#include <hip/hip_bf16.h>
#include <math.h>

#define BDIM 4
#define SLEN 4096
#define DDIM 1024
#define MROWS (BDIM*SLEN)      // 16384
#define KDIM DDIM              // 1024
#define NCHUNK 64
#define CLEN (SLEN/NCHUNK)     // 64
#define NCH (BDIM*DDIM)        // 4096
#define NKT (KDIM/32)          // 32 K-steps
#define LDSBUF 24576           // one buffer: X 16KB (8 tiles) + Wa 4KB + Wx 4KB
#define ALLROWS (MROWS + 2*DDIM)   // 18432 rows in fused cast

typedef __bf16 bf16;
typedef __bf16 bf16x8 __attribute__((ext_vector_type(8)));
typedef float f32x16 __attribute__((ext_vector_type(16)));

__device__ __forceinline__ void gload_lds16(const void* g, void* l) {
  __builtin_amdgcn_global_load_lds(
      (const __attribute__((address_space(1))) unsigned int*)g,
      (__attribute__((address_space(3))) unsigned int*)l, 16, 0, 0);
}

// ---------------- fused cast f32 -> bf16, fragment-order tile swizzle -------
// [R8-verified layout] Tile = 32 rows x 32 k (2KB) at [T][KT]; granule (r,j)
// at slot j*32 + r. Sources x / Wa / Wx concatenated by row (out buffers are
// ws-adjacent: xb | wab | wxb). Reads coalesced; writes permute in 2KB.
__global__ void cast_all_kernel(const float* __restrict__ x, const float* __restrict__ Wa,
                                const float* __restrict__ Wx, bf16* __restrict__ out) {
  const int gid  = blockIdx.x * 256 + threadIdx.x;
  const int tile = gid >> 7, local = gid & 127;
  const int j = local & 3, r = local >> 2;     // coalesced read assignment
  const int T = tile >> 5, KT = tile & 31;
  const int m = T*32 + r;
  const float* src;
  int row;
  if (m < MROWS)              { src = x;  row = m; }
  else if (m < MROWS + DDIM)  { src = Wa; row = m - MROWS; }
  else                        { src = Wx; row = m - MROWS - DDIM; }
  const float4* p = (const float4*)(src + (size_t)row * KDIM + KT*32 + j*8);
  float4 v0 = p[0], v1 = p[1];
  bf16x8 o;
  o[0] = (bf16)v0.x; o[1] = (bf16)v0.y; o[2] = (bf16)v0.z; o[3] = (bf16)v0.w;
  o[4] = (bf16)v1.x; o[5] = (bf16)v1.y; o[6] = (bf16)v1.z; o[7] = (bf16)v1.w;
  ((bf16x8*)out)[(size_t)tile * 128 + j*32 + r] = o;   // fragment-order slot
}

// ---------------- klam2[h] = -C * softplus(-Lam[h]) / ln2 ----------------
__global__ void klam_kernel(const float* __restrict__ Lam, float* __restrict__ klam) {
  int h = blockIdx.x * blockDim.x + threadIdx.x;
  if (h < DDIM) klam[h] = -8.0f * 1.4426950408889634f * log1pf(__expf(-Lam[h]));
}

// ---------------- dual-weight GEMM + gate epilogue + FUSED chunk summary ----
// [BEST MEASURED: gemm 119.4us, total 140.79] 256(M) x 64(N)-dual block,
// 8 waves (4M x 2N), per-wave 64m x 32n-dual, 32x32x16 MFMA, 3 LDS buffers
// x 24KB, counted vmcnt(3). Verified phase ordering: {ds_reads ; STAGE(t+2)}
// -> barrier -> lgkmcnt(0) -> 8 MFMA -> vmcnt(3) -> barrier.
__global__ __launch_bounds__(512, 4) void gemm_gates_kernel(
    const bf16* __restrict__ xb, const bf16* __restrict__ wab, const bf16* __restrict__ wxb,
    const float* __restrict__ ba, const float* __restrict__ bx,
    const float* __restrict__ klam, bf16* __restrict__ La, bf16* __restrict__ Bp,
    float* __restrict__ sAo, float* __restrict__ sBo)
{
  __shared__ char smem[3*LDSBUF];   // 72 KB

  const int tid  = threadIdx.x;
  const int wave = tid >> 6, lane = tid & 63;
  const int wm = wave >> 1, wn = wave & 1;       // 4M x 2N waves

  // XCD-bijective swizzle: 1024 blocks, 8 XCDs, 128 each.
  const int orig  = blockIdx.x;
  const int newid = (orig & 7) * 128 + (orig >> 3);
  const int m0 = (newid >> 4) * 256;
  const int h0 = (newid & 15) * 64;

  f32x16 accA0 = (f32x16)0.0f, accA1 = (f32x16)0.0f;
  f32x16 accX0 = (f32x16)0.0f, accX1 = (f32x16)0.0f;

  const int Tb = m0 >> 5;           // first of 8 X row-tiles
  const int Ht = h0 >> 5;           // first of 2 W row-tiles (per weight)
  const int tt = tid >> 7;          // 0..3
  const int gg = (tid & 127) * 8;   // granule elem offset
  const bf16* aS0 = xb + (size_t)(Tb + tt)     * 32768 + gg;
  const bf16* aS1 = xb + (size_t)(Tb + 4 + tt) * 32768 + gg;
  // W: threads 0-255 stage Wa (row-tiles 0,1), threads 256-511 stage Wx.
  const bf16* wS = (tid < 256)
      ? wab + (size_t)(Ht + tt)     * 32768 + gg
      : wxb + (size_t)(Ht + tt - 2) * 32768 + gg;

  auto STAGE = [&](int KT, char* nb) {
    gload_lds16(aS0 + KT*1024, nb + tid*16);            // X row-tiles 0-3
    gload_lds16(aS1 + KT*1024, nb + 8192 + tid*16);     // X row-tiles 4-7
    gload_lds16(wS  + KT*1024, nb + 16384 + tid*16);    // Wa | Wx
  };

  // per-wave ds_read offsets (all base + lane*16 -> conflict-free)
  const int aOff = wm*4096  + lane*16;              // subtiles 2wm, 2wm+1
  const int bOa  = 16384 + wn*2048 + lane*16;       // Wa tile wn
  const int bOx  = 20480 + wn*2048 + lane*16;       // Wx tile wn

  char* b0 = smem;
  char* b1 = smem + LDSBUF;
  char* b2 = smem + 2*LDSBUF;

  STAGE(0, b0);
  STAGE(1, b1);
  asm volatile("s_waitcnt vmcnt(3)" ::: "memory");   // tile 0 landed
  __builtin_amdgcn_s_barrier();

  char *pc = b0, *pn = b1, *ps = b2;
  for (int kt = 0; kt < NKT; ++kt) {
    // ---- phase 1: issue ds_reads for tile kt, then prefetch tile kt+2 ----
    bf16x8 a00 = *(const bf16x8*)(pc + aOff);            // subtile 2wm, kg0
    bf16x8 a01 = *(const bf16x8*)(pc + aOff + 1024);     // subtile 2wm, kg1
    bf16x8 a10 = *(const bf16x8*)(pc + aOff + 2048);     // subtile 2wm+1, kg0
    bf16x8 a11 = *(const bf16x8*)(pc + aOff + 3072);     // subtile 2wm+1, kg1
    bf16x8 ba0 = *(const bf16x8*)(pc + bOa);
    bf16x8 ba1 = *(const bf16x8*)(pc + bOa + 1024);
    bf16x8 bx0 = *(const bf16x8*)(pc + bOx);
    bf16x8 bx1 = *(const bf16x8*)(pc + bOx + 1024);
    __builtin_amdgcn_sched_barrier(0);                 // pin ds_reads here

    if (kt + 2 < NKT) STAGE(kt + 2, ps);

    __builtin_amdgcn_s_barrier();                      // rendezvous absorbs ds latency
    asm volatile("s_waitcnt lgkmcnt(0)" ::: "memory"); // ~free now
    __builtin_amdgcn_sched_barrier(0);                 // rule #18: no MFMA hoist

    __builtin_amdgcn_s_setprio(1);
    accA0 = __builtin_amdgcn_mfma_f32_32x32x16_bf16(a00, ba0, accA0, 0, 0, 0);
    accA1 = __builtin_amdgcn_mfma_f32_32x32x16_bf16(a10, ba0, accA1, 0, 0, 0);
    accX0 = __builtin_amdgcn_mfma_f32_32x32x16_bf16(a00, bx0, accX0, 0, 0, 0);
    accX1 = __builtin_amdgcn_mfma_f32_32x32x16_bf16(a10, bx0, accX1, 0, 0, 0);
    accA0 = __builtin_amdgcn_mfma_f32_32x32x16_bf16(a01, ba1, accA0, 0, 0, 0);
    accA1 = __builtin_amdgcn_mfma_f32_32x32x16_bf16(a11, ba1, accA1, 0, 0, 0);
    accX0 = __builtin_amdgcn_mfma_f32_32x32x16_bf16(a01, bx1, accX0, 0, 0, 0);
    accX1 = __builtin_amdgcn_mfma_f32_32x32x16_bf16(a11, bx1, accX1, 0, 0, 0);
    __builtin_amdgcn_s_setprio(0);

    // ---- end-of-step: ensure tile kt+1 fully landed for next step's reads ----
    if (kt + 2 < NKT)      { asm volatile("s_waitcnt vmcnt(3)" ::: "memory"); }
    else if (kt + 1 < NKT) { asm volatile("s_waitcnt vmcnt(0)" ::: "memory"); }
    if (kt + 1 < NKT) __builtin_amdgcn_s_barrier();

    char* tmp = pc; pc = pn; pn = ps; ps = tmp;
  }

  // ---- epilogue ----
  // C/D layout (32x32): col = lane&31, row = (q&3) + 8*(q>>2) + 4*(lane>>5)
  const int colh = h0 + wn*32 + (lane & 31);
  const int hi   = lane >> 5;
  const float bah = ba[colh], bxh = bx[colh], kl = klam[colh];  // kl pre-scaled by 1/ln2
  // x reload from fragment-order xb [R8-verified]
  const size_t xh = (size_t)(colh >> 5) * 1024 + ((colh >> 3) & 3) * 256 + (colh & 7);

  // segment maps: P/S over 4 consecutive rows (g-group), per mt and this hi.
  float P[2][4], S[2][4];
  #pragma unroll
  for (int mt = 0; mt < 2; ++mt) {
    const int mbase = m0 + wm*64 + mt*32;
    const size_t xtb = (size_t)(mbase >> 5) * 32768 + xh;
    const f32x16 aA = mt ? accA1 : accA0;
    const f32x16 aX = mt ? accX1 : accX0;
    #pragma unroll
    for (int g = 0; g < 4; ++g) {
      float Pg = 1.0f, Sg = 0.0f;
      #pragma unroll
      for (int jj = 0; jj < 4; ++jj) {
        const int q   = g*4 + jj;
        const int row = jj + 8*g + 4*hi;          // rows increase with jj
        const int m   = mbase + row;
        const float ga = aA[q] + bah;
        const float gx = aX[q] + bxh;
        const float rt = 1.0f / (1.0f + __expf(-ga));
        const float it = 1.0f / (1.0f + __expf(-gx));
        const float la = kl * rt;                 // log2(a)
        const float a  = exp2f(la);
        const float xv = (float)xb[xtb + (size_t)row * 8];
        const float bb = sqrtf(fmaxf(1.0f - a*a, 0.0f)) * (it * xv);
        La[(size_t)m * DDIM + colh] = (bf16)la;   // log2(a) -> ws (bf16)
        Bp[(size_t)m * DDIM + colh] = (bf16)bb;   // b -> ws (bf16)
        Sg = fmaf(a, Sg, bb);                     // exact a in the summary
        Pg *= a;
      }
      P[mt][g] = Pg; S[mt][g] = Sg;
    }
  }

  // compose the 16 segments in row order: sigma = mt*8 + g*2 + hi'
  float Pc = 1.0f, Sc = 0.0f;
  #pragma unroll
  for (int mt = 0; mt < 2; ++mt) {
    #pragma unroll
    for (int g = 0; g < 4; ++g) {
      const float pm = P[mt][g], sm = S[mt][g];
      const float pp = __shfl_xor(pm, 32);
      const float sp = __shfl_xor(sm, 32);
      const float p0 = hi ? pp : pm, s0 = hi ? sp : sm;   // hi'=0 first
      const float p1 = hi ? pm : pp, s1 = hi ? sm : sp;   // then hi'=1
      Sc = fmaf(p0, Sc, s0); Pc *= p0;
      Sc = fmaf(p1, Sc, s1); Pc *= p1;
    }
  }
  if (hi == 0) {
    const int mb0  = m0 + wm*64;          // chunk start (64-aligned)
    const int bidx = mb0 >> 12;           // batch
    const int c    = (mb0 & (SLEN-1)) >> 6;  // chunk within sequence
    sAo[(size_t)c * NCH + bidx*1024 + colh] = Pc;
    sBo[(size_t)c * NCH + bidx*1024 + colh] = Sc;
  }
}

// ---------------- phase 2: sequential prefix over chunks ----------------
__global__ void scan2_kernel(const float* __restrict__ sA, const float* __restrict__ sB,
                             float* __restrict__ Hin) {
  const int ch = blockIdx.x * 256 + threadIdx.x;
  float h = 0.0f;
  for (int c = 0; c < NCHUNK; ++c) {
    Hin[c * NCH + ch] = h;
    h = fmaf(sA[c * NCH + ch], h, sB[c * NCH + ch]);
  }
}

// ---------------- phase 3: apply, channel-pair vectorized ----------------
// Each thread owns channels (d, d+1): uint load = 2 x bf16 (bf16->f32 is a
// free <<16 bit-op), float2 store. Halves load instructions vs scalar bf16.
__global__ void scan3_kernel(const bf16* __restrict__ La, const bf16* __restrict__ Bp,
                             const float* __restrict__ Hin, float* __restrict__ y) {
  const int p = blockIdx.x * 256 + threadIdx.x;    // 0..2047 = b*512 + dpair
  const int c = blockIdx.y;
  const int b = p >> 9, d = (p & 511) * 2;
  size_t idx = ((size_t)b * SLEN + (size_t)c * CLEN) * DDIM + d;
  const float2 hin = *(const float2*)(Hin + c * NCH + b * 1024 + d);
  float h0 = hin.x, h1 = hin.y;
  #pragma unroll 4
  for (int s = 0; s < CLEN; ++s) {
    const unsigned la2 = *(const unsigned*)(La + idx);
    const unsigned bp2 = *(const unsigned*)(Bp + idx);
    const float a0 = exp2f(__uint_as_float(la2 << 16));
    const float a1 = exp2f(__uint_as_float(la2 & 0xFFFF0000u));
    h0 = fmaf(a0, h0, __uint_as_float(bp2 << 16));
    h1 = fmaf(a1, h1, __uint_as_float(bp2 & 0xFFFF0000u));
    *(float2*)(y + idx) = make_float2(h0, h1);
    idx += DDIM;
  }
}

extern "C" void kernel_launch(void* const* d_in, const int* in_sizes, int n_in,
                              void* d_out, int out_size, void* d_ws, size_t ws_size,
                              hipStream_t stream) {
  const float* x   = (const float*)d_in[0];
  const float* Wa  = (const float*)d_in[1];
  const float* Wx  = (const float*)d_in[2];
  const float* ba  = (const float*)d_in[3];
  const float* bx  = (const float*)d_in[4];
  const float* Lam = (const float*)d_in[5];
  float* y = (float*)d_out;

  // workspace layout (bytes): total 108,007,424 (proven budget)
  if (ws_size < 108007424ULL) return;  // insufficient scratch; fail cleanly
  char* ws = (char*)d_ws;
  bf16*  xb   = (bf16*)(ws);                     // 32 MB: x bf16, frag-order
  bf16*  wab  = (bf16*)(ws + 33554432);          //  2 MB, frag-order (adjacent!)
  bf16*  wxb  = (bf16*)(ws + 35651584);          //  2 MB, frag-order (adjacent!)
  bf16*  Bp   = (bf16*)(ws + 37748736);          // 32 MB: b (bf16)
  bf16*  La   = (bf16*)(ws + 71303168);          // 32 MB: log2(a) (bf16)
  float* klam = (float*)(ws + 104857600);        //  4 KB (pre-scaled by 1/ln2)
  float* sA   = (float*)(ws + 104861696);        //  1 MB
  float* sB   = (float*)(ws + 105910272);        //  1 MB
  float* Hin  = (float*)(ws + 106958848);        //  1 MB

  // fused cast: 18432 rows x 1024 k -> 576 row-tiles x 32 k-tiles x 128 granules
  cast_all_kernel<<<(ALLROWS/32)*(KDIM/32)*128/256, 256, 0, stream>>>(x, Wa, Wx, xb);
  klam_kernel<<<DDIM/256, 256, 0, stream>>>(Lam, klam);

  // 1024 blocks: (M/256) * (N/64) = 64 * 16
  gemm_gates_kernel<<<1024, 512, 0, stream>>>(xb, wab, wxb, ba, bx, klam,
                                              La, Bp, sA, sB);

  scan2_kernel<<<NCH/256, 256, 0, stream>>>(sA, sB, Hin);
  dim3 sgrid(2048/256, NCHUNK);
  scan3_kernel<<<sgrid, 256, 0, stream>>>(La, Bp, Hin, y);
}